// Round 6
// baseline (178.175 us; speedup 1.0000x reference)
//
#include <hip/hip_runtime.h>

#define NN 8000
#define NE 64000
#define INF 16
#define HH 128
#define MM 16
#define EDF 4
#define OUTF 4
#define NL 2
#define BN_EPS 1e-5f
#define BPR 2064          // Bp rows per layer: 2048 cols + 16 b2-cols
#define QS 2052           // sQ node stride in halfs (conflict-free)

typedef __attribute__((ext_vector_type(8))) short short8;
typedef __attribute__((ext_vector_type(4))) float f32x4;

static __device__ __forceinline__ unsigned short f2bf(float f) {
  unsigned u = __builtin_bit_cast(unsigned, f);
  u = (u + 0x7fffu + ((u >> 16) & 1u)) >> 16;
  return (unsigned short)u;
}

// bijective k-permutation: qperm(ks*32+l4*8+j) = l4 + 4*j + 32*ks
static __device__ __forceinline__ int qperm(int k) {
  return ((k >> 3) & 3) | ((k & 7) << 2) | (k & 0x60);
}

// in_proj (all 8000 blocks) + edge counting (blocks 0..499) + Bp build (blocks 500..4627)
__global__ __launch_bounds__(128) void front_k(
    const float* __restrict__ x, const float* __restrict__ inW,
    const float* __restrict__ inb, const int* __restrict__ ei,
    const float* __restrict__ W2, const float* __restrict__ b2,
    float* __restrict__ h, unsigned short* __restrict__ hb,
    float* __restrict__ deg, int* __restrict__ cnt,
    unsigned short* __restrict__ Bp) {
  int blk = blockIdx.x;
  int t = threadIdx.x;
  __shared__ float sx[INF];
  if (t < INF) sx[t] = x[blk * INF + t];
  __syncthreads();
  float acc = inb[t];
#pragma unroll
  for (int i = 0; i < INF; ++i) acc = fmaf(sx[i], inW[i * HH + t], acc);
  h[(size_t)blk * HH + t] = acc;
  hb[(size_t)blk * HH + t] = f2bf(acc);

  if (blk < 500) {
    int e = blk * 128 + t;
    atomicAdd(&deg[ei[NE + e]], 1.0f);
    atomicAdd(&cnt[ei[e]], 1);
  } else if (blk < 500 + 2 * BPR) {
    int r = blk - 500;
    int l = r / BPR;
    int c = r - l * BPR;
    float v;
    if (c < 2048) {
      int k = c >> 4, m = c & 15;
      v = W2[(size_t)l * (HH * HH * MM) + (size_t)k * 2048 + t * 16 + m];
    } else {
      int m = c - 2048;
      v = b2[l * 2048 + t * 16 + m];
    }
    Bp[((size_t)l * BPR + c) * HH + t] = f2bf(v);
  }
}

__global__ __launch_bounds__(1024) void scan_k(const int* __restrict__ cnt,
                                               int* __restrict__ base) {
  __shared__ int part[1024];
  int t = threadIdx.x;
  int v[8], s = 0;
#pragma unroll
  for (int j = 0; j < 8; ++j) {
    int idx = t * 8 + j;
    v[j] = (idx < NN) ? cnt[idx] : 0;
    s += v[j];
  }
  part[t] = s;
  __syncthreads();
  for (int off = 1; off < 1024; off <<= 1) {
    int x = (t >= off) ? part[t - off] : 0;
    __syncthreads();
    part[t] += x;
    __syncthreads();
  }
  int ex = (t > 0) ? part[t - 1] : 0;
#pragma unroll
  for (int j = 0; j < 8; ++j) {
    int idx = t * 8 + j;
    if (idx < NN) base[idx] = ex;
    ex += v[j];
  }
  if (t == 1023) base[NN] = part[1023];
}

__global__ void scatter_k(const int* __restrict__ ei, const float* __restrict__ ea,
                          const int* __restrict__ base, int* __restrict__ cur,
                          float* __restrict__ ea_s, int* __restrict__ dst_s) {
  int e = blockIdx.x * blockDim.x + threadIdx.x;
  if (e < NE) {
    int src = ei[e];
    int p = base[src] + atomicAdd(&cur[src], 1);
    *(float4*)&ea_s[(size_t)p * 4] = *(const float4*)&ea[(size_t)e * 4];
    dst_s[p] = ei[NE + e];
  }
}

// Per block: 16 src nodes. Phase 1: Qn_tile[16x2048] = A[16x128] @ Bp^T into LDS
// (bf16, [node][qperm(k)][m], stride QS) + B2 mini-tile. Phase 2: per-node edge
// contraction P = relu1 @ Qn_tile[node] via MFMA, atomics into agg.
__global__ __launch_bounds__(256) void fused_layer_k(
    const unsigned short* __restrict__ hb, const float* __restrict__ hpre,
    const float* __restrict__ bnsums, const float* __restrict__ gamma,
    const float* __restrict__ beta, int bn_mode,
    const unsigned short* __restrict__ Bp,
    const float* __restrict__ ea_s, const int* __restrict__ dst_s,
    const int* __restrict__ base, const float* __restrict__ W1,
    const float* __restrict__ b1, float* __restrict__ agg) {
  __shared__ unsigned short sA[16 * 136];
  __shared__ unsigned short sQ[16 * QS];
  __shared__ float sW1[EDF * HH];
  __shared__ float sb1[HH];
  __shared__ float sB2[16][17];
  __shared__ float sscl[HH], sshf[HH];

  int tid = threadIdx.x;
  int n0 = blockIdx.x * 16;
  int wid = tid >> 6, lane = tid & 63;
  int l15 = lane & 15, l4 = lane >> 4;

  for (int i = tid; i < EDF * HH; i += 256) sW1[i] = W1[i];
  if (tid < HH) sb1[tid] = b1[tid];
  if (bn_mode && tid < HH) {
    float mu = bnsums[tid] * (1.0f / NN);
    float var = bnsums[HH + tid] * (1.0f / NN) - mu * mu;
    float sc = gamma[tid] * rsqrtf(var + BN_EPS);
    sscl[tid] = sc;
    sshf[tid] = beta[tid] - mu * sc;
  }
  __syncthreads();

  // stage A tile: thread t -> node t>>4, 8 halfs at col (t&15)*8
  {
    int node = tid >> 4, c0 = (tid & 15) * 8;
    if (bn_mode == 0) {
      uint4 v = *(const uint4*)&hb[(size_t)(n0 + node) * HH + c0];
      *(uint4*)&sA[node * 136 + c0] = v;
    } else {
      float4 v0 = *(const float4*)&hpre[(size_t)(n0 + node) * HH + c0];
      float4 v1 = *(const float4*)&hpre[(size_t)(n0 + node) * HH + c0 + 4];
      short8 o;
#pragma unroll
      for (int j = 0; j < 4; ++j) {
        o[j] = (short)f2bf(fmaxf(0.f, fmaf((&v0.x)[j], sscl[c0 + j], sshf[c0 + j])));
        o[4 + j] = (short)f2bf(fmaxf(0.f, fmaf((&v1.x)[j], sscl[c0 + 4 + j], sshf[c0 + 4 + j])));
      }
      *(short8*)&sA[node * 136 + c0] = o;
    }
  }
  __syncthreads();

  // A-frags: a[ks] = A[node=l15][k=ks*32+l4*8 ..+8], reused across all ctiles
  short8 a0 = *(const short8*)&sA[l15 * 136 + 0 * 32 + l4 * 8];
  short8 a1 = *(const short8*)&sA[l15 * 136 + 1 * 32 + l4 * 8];
  short8 a2 = *(const short8*)&sA[l15 * 136 + 2 * 32 + l4 * 8];
  short8 a3 = *(const short8*)&sA[l15 * 136 + 3 * 32 + l4 * 8];

  // GEMM phase: wave w handles ctiles [w*32, w*32+32); ctile == k index
  int ctb = wid * 32;
#pragma unroll 2
  for (int ct = ctb; ct < ctb + 32; ++ct) {
    const unsigned short* bp = Bp + ((size_t)(ct * 16 + l15)) * HH + l4 * 8;
    short8 b0 = *(const short8*)(bp);
    short8 bv1 = *(const short8*)(bp + 32);
    short8 bv2 = *(const short8*)(bp + 64);
    short8 bv3 = *(const short8*)(bp + 96);
    f32x4 acc = {0.f, 0.f, 0.f, 0.f};
    acc = __builtin_amdgcn_mfma_f32_16x16x32_bf16(a0, b0, acc, 0, 0, 0);
    acc = __builtin_amdgcn_mfma_f32_16x16x32_bf16(a1, bv1, acc, 0, 0, 0);
    acc = __builtin_amdgcn_mfma_f32_16x16x32_bf16(a2, bv2, acc, 0, 0, 0);
    acc = __builtin_amdgcn_mfma_f32_16x16x32_bf16(a3, bv3, acc, 0, 0, 0);
    int kq = qperm(ct);
#pragma unroll
    for (int j = 0; j < 4; ++j)
      sQ[(l4 * 4 + j) * QS + kq * 16 + l15] = f2bf(acc[j]);
  }
  if (wid == 3) {  // B2 ctile: Bp rows 2048..2063
    const unsigned short* bp = Bp + ((size_t)(2048 + l15)) * HH + l4 * 8;
    short8 b0 = *(const short8*)(bp);
    short8 bv1 = *(const short8*)(bp + 32);
    short8 bv2 = *(const short8*)(bp + 64);
    short8 bv3 = *(const short8*)(bp + 96);
    f32x4 acc = {0.f, 0.f, 0.f, 0.f};
    acc = __builtin_amdgcn_mfma_f32_16x16x32_bf16(a0, b0, acc, 0, 0, 0);
    acc = __builtin_amdgcn_mfma_f32_16x16x32_bf16(a1, bv1, acc, 0, 0, 0);
    acc = __builtin_amdgcn_mfma_f32_16x16x32_bf16(a2, bv2, acc, 0, 0, 0);
    acc = __builtin_amdgcn_mfma_f32_16x16x32_bf16(a3, bv3, acc, 0, 0, 0);
#pragma unroll
    for (int j = 0; j < 4; ++j) sB2[l4 * 4 + j][l15] = acc[j];
  }
  __syncthreads();

  // Contract phase: wave handles 4 nodes sequentially
  for (int ni = 0; ni < 4; ++ni) {
    int nl = wid * 4 + ni;
    int n = n0 + nl;
    int i0 = base[n], i1 = base[n + 1];
    if (i0 == i1) continue;

    short8 qb[4];
#pragma unroll
    for (int ks = 0; ks < 4; ++ks)
#pragma unroll
      for (int j = 0; j < 8; ++j)
        qb[ks][j] = (short)sQ[nl * QS + qperm(ks * 32 + l4 * 8 + j) * 16 + l15];
    float b2v = sB2[nl][l15];

    for (int t0 = i0; t0 < i1; t0 += 16) {
      int row = t0 + l15;
      bool valid = row < i1;
      float4 eav = valid ? *(const float4*)&ea_s[(size_t)row * 4]
                         : make_float4(0.f, 0.f, 0.f, 0.f);
      f32x4 acc = {0.f, 0.f, 0.f, 0.f};
#pragma unroll
      for (int ks = 0; ks < 4; ++ks) {
        short8 a;
#pragma unroll
        for (int j = 0; j < 8; ++j) {
          int k = ks * 32 + l4 * 8 + j;
          float r = fmaf(eav.w, sW1[3 * HH + k],
                     fmaf(eav.z, sW1[2 * HH + k],
                       fmaf(eav.y, sW1[HH + k], fmaf(eav.x, sW1[k], sb1[k]))));
          a[j] = valid ? (short)f2bf(fmaxf(r, 0.f)) : (short)0;
        }
        acc = __builtin_amdgcn_mfma_f32_16x16x32_bf16(a, qb[ks], acc, 0, 0, 0);
      }
#pragma unroll
      for (int j = 0; j < 4; ++j) {
        int r = t0 + l4 * 4 + j;
        if (r < i1) {
          int dst = dst_s[r];
          atomicAdd(&agg[(size_t)dst * MM + l15], acc[j] + b2v);
        }
      }
    }
  }
}

// 16 nodes/block; optional inline BN+relu; zeroes its agg slice for next layer.
__global__ __launch_bounds__(256) void node_update_k(
    const float* __restrict__ hplain, const float* __restrict__ hsrc_pre,
    const float* __restrict__ bnsums, const float* __restrict__ gamma,
    const float* __restrict__ beta, int bn_mode,
    float* __restrict__ agg, const float* __restrict__ deg,
    const float* __restrict__ rootW, const float* __restrict__ cbias,
    const float* __restrict__ msgW, const float* __restrict__ msgb,
    float* __restrict__ hpre, float* __restrict__ sums) {
  __shared__ float srw[HH * MM];
  __shared__ float smw[MM * HH];
  __shared__ float sh[16][HH];
  __shared__ float xm[16][MM];
  __shared__ float scb[MM];
  __shared__ float smb[HH];
  __shared__ float red[256];
  __shared__ float sscl[HH], sshf[HH];
  int tid = threadIdx.x;
  int n0 = blockIdx.x * 16;
  for (int i = tid; i < HH * MM; i += 256) {
    srw[i] = rootW[i];
    smw[i] = msgW[i];
  }
  if (tid < MM) scb[tid] = cbias[tid];
  if (tid < HH) smb[tid] = msgb[tid];
  if (bn_mode && tid < HH) {
    float mu = bnsums[tid] * (1.0f / NN);
    float var = bnsums[HH + tid] * (1.0f / NN) - mu * mu;
    float sc = gamma[tid] * rsqrtf(var + BN_EPS);
    sscl[tid] = sc;
    sshf[tid] = beta[tid] - mu * sc;
  }
  __syncthreads();
  for (int i = tid; i < 16 * HH; i += 256) {
    int ni = i >> 7, c = i & 127;
    if (bn_mode) {
      float v = hsrc_pre[(size_t)(n0 + ni) * HH + c];
      sh[ni][c] = fmaxf(0.f, fmaf(v, sscl[c], sshf[c]));
    } else {
      sh[ni][c] = hplain[(size_t)(n0 + ni) * HH + c];
    }
  }
  __syncthreads();

  {
    int ni = tid >> 4, m = tid & 15;
    float s = 0.f;
#pragma unroll
    for (int k = 0; k < HH; ++k) s = fmaf(sh[ni][k], srw[k * MM + m], s);
    int n = n0 + ni;
    xm[ni][m] = agg[(size_t)n * MM + m] / fmaxf(deg[n], 1.0f) + s + scb[m];
  }
  __syncthreads();
  agg[(size_t)n0 * MM + tid] = 0.f;  // zero this block's slice for next layer

  int t = tid & 127;
  float lsum = 0.f, lss = 0.f;
#pragma unroll
  for (int pass = 0; pass < 8; ++pass) {
    int ni = pass * 2 + (tid >> 7);
    float hp = sh[ni][t] + smb[t];
#pragma unroll
    for (int m = 0; m < MM; ++m) hp = fmaf(xm[ni][m], smw[m * HH + t], hp);
    hpre[(size_t)(n0 + ni) * HH + t] = hp;
    lsum += hp;
    lss = fmaf(hp, hp, lss);
  }
  red[tid] = lsum;
  __syncthreads();
  if (tid < 128) atomicAdd(&sums[t], red[tid] + red[tid + 128]);
  __syncthreads();
  red[tid] = lss;
  __syncthreads();
  if (tid < 128) atomicAdd(&sums[HH + t], red[tid] + red[tid + 128]);
}

__global__ void out_proj_k(const float* __restrict__ hpre,
                           const float* __restrict__ bnsums,
                           const float* __restrict__ gamma,
                           const float* __restrict__ beta,
                           const float* __restrict__ W, const float* __restrict__ b,
                           float* __restrict__ out) {
  __shared__ float sscl[HH], sshf[HH];
  int tid = threadIdx.x;
  if (tid < HH) {
    float mu = bnsums[tid] * (1.0f / NN);
    float var = bnsums[HH + tid] * (1.0f / NN) - mu * mu;
    float sc = gamma[tid] * rsqrtf(var + BN_EPS);
    sscl[tid] = sc;
    sshf[tid] = beta[tid] - mu * sc;
  }
  __syncthreads();
  int n = blockIdx.x * 4 + (tid >> 6);
  int lane = tid & 63;
  if (n >= NN) return;
  float acc0 = 0.f, acc1 = 0.f, acc2 = 0.f, acc3 = 0.f;
#pragma unroll
  for (int rep = 0; rep < 2; ++rep) {
    int hh = lane + rep * 64;
    float hv = fmaxf(0.f, fmaf(hpre[(size_t)n * HH + hh], sscl[hh], sshf[hh]));
    acc0 = fmaf(hv, W[hh * OUTF + 0], acc0);
    acc1 = fmaf(hv, W[hh * OUTF + 1], acc1);
    acc2 = fmaf(hv, W[hh * OUTF + 2], acc2);
    acc3 = fmaf(hv, W[hh * OUTF + 3], acc3);
  }
#pragma unroll
  for (int s = 32; s > 0; s >>= 1) {
    acc0 += __shfl_down(acc0, s);
    acc1 += __shfl_down(acc1, s);
    acc2 += __shfl_down(acc2, s);
    acc3 += __shfl_down(acc3, s);
  }
  if (lane == 0) {
    out[n * OUTF + 0] = acc0 + b[0];
    out[n * OUTF + 1] = acc1 + b[1];
    out[n * OUTF + 2] = acc2 + b[2];
    out[n * OUTF + 3] = acc3 + b[3];
  }
}

extern "C" void kernel_launch(void* const* d_in, const int* in_sizes, int n_in,
                              void* d_out, int out_size, void* d_ws, size_t ws_size,
                              hipStream_t stream) {
  (void)in_sizes; (void)n_in; (void)out_size; (void)ws_size;
  const float* x    = (const float*)d_in[0];
  const int* ei     = (const int*)d_in[1];
  const float* ea   = (const float*)d_in[2];
  const float* inW  = (const float*)d_in[3];
  const float* inb  = (const float*)d_in[4];
  const float* cW1  = (const float*)d_in[5];
  const float* cb1  = (const float*)d_in[6];
  const float* cW2  = (const float*)d_in[7];
  const float* cb2  = (const float*)d_in[8];
  const float* rW   = (const float*)d_in[9];
  const float* cbias= (const float*)d_in[10];
  const float* gam  = (const float*)d_in[11];
  const float* bet  = (const float*)d_in[12];
  const float* mW   = (const float*)d_in[13];
  const float* mb   = (const float*)d_in[14];
  const float* oW   = (const float*)d_in[15];
  const float* ob   = (const float*)d_in[16];
  float* out = (float*)d_out;

  float* ws = (float*)d_ws;
  size_t off = 0;
  // contiguous zero region: deg, cnt, cur, agg, sums0, sums1
  float* deg   = ws + off; off += 8192;
  int* cnt     = (int*)(ws + off); off += 8192;
  int* cur     = (int*)(ws + off); off += 8192;
  float* agg   = ws + off; off += (size_t)NN * MM;
  float* sums0 = ws + off; off += 256;
  float* sums1 = ws + off; off += 256;
  size_t zero_floats = off;
  float* h     = ws + off; off += (size_t)NN * HH;
  float* hpre0 = ws + off; off += (size_t)NN * HH;
  float* hpre1 = ws + off; off += (size_t)NN * HH;
  unsigned short* hb = (unsigned short*)(ws + off); off += (size_t)NN * HH / 2;
  unsigned short* Bp = (unsigned short*)(ws + off); off += (size_t)NL * BPR * HH / 2;
  int* basev   = (int*)(ws + off); off += 8192;
  float* ea_s  = ws + off; off += (size_t)NE * 4;
  int* dst_s   = (int*)(ws + off); off += NE;

  hipMemsetAsync(deg, 0, zero_floats * sizeof(float), stream);
  front_k<<<NN, 128, 0, stream>>>(x, inW, inb, ei, cW2, cb2, h, hb, deg, cnt, Bp);
  scan_k<<<1, 1024, 0, stream>>>(cnt, basev);
  scatter_k<<<(NE + 255) / 256, 256, 0, stream>>>(ei, ea, basev, cur, ea_s, dst_s);

  // ---- layer 0 ----
  fused_layer_k<<<NN / 16, 256, 0, stream>>>(hb, hpre0, sums0, gam, bet, 0,
                                             Bp, ea_s, dst_s, basev, cW1, cb1, agg);
  node_update_k<<<NN / 16, 256, 0, stream>>>(h, hpre0, sums0, gam, bet, 0,
                                             agg, deg, rW, cbias, mW, mb,
                                             hpre0, sums0);
  // ---- layer 1 ----
  fused_layer_k<<<NN / 16, 256, 0, stream>>>(hb, hpre0, sums0, gam, bet, 1,
                                             Bp + (size_t)BPR * HH, ea_s, dst_s, basev,
                                             cW1 + EDF * HH, cb1 + HH, agg);
  node_update_k<<<NN / 16, 256, 0, stream>>>(h, hpre0, sums0, gam, bet, 1,
                                             agg, deg, rW + HH * MM, cbias + MM,
                                             mW + MM * HH, mb + HH,
                                             hpre1, sums1);
  out_proj_k<<<NN / 4, 256, 0, stream>>>(hpre1, sums1, gam + HH, bet + HH,
                                         oW, ob, out);
}

// Round 7
// 163.460 us; speedup vs baseline: 1.0900x; 1.0900x over previous
//
#include <hip/hip_runtime.h>

#define NN 8000
#define NE 64000
#define INF 16
#define HH 128
#define MM 16
#define EDF 4
#define OUTF 4
#define NL 2
#define BN_EPS 1e-5f
#define BPR 2064          // Bp rows per layer: 2048 cols + 16 b2-cols
#define QS 2052           // sQ node stride in halfs (conflict-free)

typedef __attribute__((ext_vector_type(8))) short short8;
typedef __attribute__((ext_vector_type(4))) float f32x4;

static __device__ __forceinline__ unsigned short f2bf(float f) {
  unsigned u = __builtin_bit_cast(unsigned, f);
  u = (u + 0x7fffu + ((u >> 16) & 1u)) >> 16;
  return (unsigned short)u;
}

// bijective k-permutation: qperm(ks*32+l4*8+j) = l4 + 4*j + 32*ks
static __device__ __forceinline__ int qperm(int k) {
  return ((k >> 3) & 3) | ((k & 7) << 2) | (k & 0x60);
}

// in_proj (all 8000 blocks) + edge counting (blocks 0..499) +
// coalesced Bp build (blocks 500..755 = W2 k-rows, 756..757 = b2 rows)
__global__ __launch_bounds__(128) void front_k(
    const float* __restrict__ x, const float* __restrict__ inW,
    const float* __restrict__ inb, const int* __restrict__ ei,
    const float* __restrict__ W2, const float* __restrict__ b2,
    float* __restrict__ h, unsigned short* __restrict__ hb,
    float* __restrict__ deg, int* __restrict__ cnt,
    unsigned short* __restrict__ Bp) {
  int blk = blockIdx.x;
  int t = threadIdx.x;
  __shared__ float sx[INF];
  if (t < INF) sx[t] = x[blk * INF + t];
  __syncthreads();
  float acc = inb[t];
#pragma unroll
  for (int i = 0; i < INF; ++i) acc = fmaf(sx[i], inW[i * HH + t], acc);
  h[(size_t)blk * HH + t] = acc;
  hb[(size_t)blk * HH + t] = f2bf(acc);

  if (blk < 500) {
    int e = blk * 128 + t;
    atomicAdd(&deg[ei[NE + e]], 1.0f);
    atomicAdd(&cnt[ei[e]], 1);
  } else if (blk < 756) {
    // transpose one W2 row k: read 2048 f32 contiguous, write 16 Bp rows coalesced
    int r = blk - 500;            // 0..255
    int l = r >> 7, k = r & 127;
    const float* w2row = W2 + (size_t)l * (HH * HH * MM) + (size_t)k * 2048;
    float4 v0 = *(const float4*)&w2row[t * 16 + 0];
    float4 v1 = *(const float4*)&w2row[t * 16 + 4];
    float4 v2 = *(const float4*)&w2row[t * 16 + 8];
    float4 v3 = *(const float4*)&w2row[t * 16 + 12];
    unsigned short* bpr = Bp + ((size_t)l * BPR + (size_t)k * 16) * HH + t;
#pragma unroll
    for (int j = 0; j < 4; ++j) bpr[(0 + j) * HH] = f2bf((&v0.x)[j]);
#pragma unroll
    for (int j = 0; j < 4; ++j) bpr[(4 + j) * HH] = f2bf((&v1.x)[j]);
#pragma unroll
    for (int j = 0; j < 4; ++j) bpr[(8 + j) * HH] = f2bf((&v2.x)[j]);
#pragma unroll
    for (int j = 0; j < 4; ++j) bpr[(12 + j) * HH] = f2bf((&v3.x)[j]);
  } else if (blk < 758) {
    int l = blk - 756;
    const float* b2row = b2 + (size_t)l * 2048;
    float4 v0 = *(const float4*)&b2row[t * 16 + 0];
    float4 v1 = *(const float4*)&b2row[t * 16 + 4];
    float4 v2 = *(const float4*)&b2row[t * 16 + 8];
    float4 v3 = *(const float4*)&b2row[t * 16 + 12];
    unsigned short* bpr = Bp + ((size_t)l * BPR + 2048) * HH + t;
#pragma unroll
    for (int j = 0; j < 4; ++j) bpr[(0 + j) * HH] = f2bf((&v0.x)[j]);
#pragma unroll
    for (int j = 0; j < 4; ++j) bpr[(4 + j) * HH] = f2bf((&v1.x)[j]);
#pragma unroll
    for (int j = 0; j < 4; ++j) bpr[(8 + j) * HH] = f2bf((&v2.x)[j]);
#pragma unroll
    for (int j = 0; j < 4; ++j) bpr[(12 + j) * HH] = f2bf((&v3.x)[j]);
  }
}

__global__ __launch_bounds__(1024) void scan_k(const int* __restrict__ cnt,
                                               int* __restrict__ base) {
  __shared__ int part[1024];
  int t = threadIdx.x;
  int v[8], s = 0;
#pragma unroll
  for (int j = 0; j < 8; ++j) {
    int idx = t * 8 + j;
    v[j] = (idx < NN) ? cnt[idx] : 0;
    s += v[j];
  }
  part[t] = s;
  __syncthreads();
  for (int off = 1; off < 1024; off <<= 1) {
    int x = (t >= off) ? part[t - off] : 0;
    __syncthreads();
    part[t] += x;
    __syncthreads();
  }
  int ex = (t > 0) ? part[t - 1] : 0;
#pragma unroll
  for (int j = 0; j < 8; ++j) {
    int idx = t * 8 + j;
    if (idx < NN) base[idx] = ex;
    ex += v[j];
  }
  if (t == 1023) base[NN] = part[1023];
}

__global__ void scatter_k(const int* __restrict__ ei, const float* __restrict__ ea,
                          const int* __restrict__ base, int* __restrict__ cur,
                          float* __restrict__ ea_s, int* __restrict__ dst_s) {
  int e = blockIdx.x * blockDim.x + threadIdx.x;
  if (e < NE) {
    int src = ei[e];
    int p = base[src] + atomicAdd(&cur[src], 1);
    *(float4*)&ea_s[(size_t)p * 4] = *(const float4*)&ea[(size_t)e * 4];
    dst_s[p] = ei[NE + e];
  }
}

// Per block (512 thr, 8 waves): 16 src nodes.
// Phase 1: Qn_tile[16x2048] = A[16x128] @ Bp^T into LDS + B2 mini-tile.
// Phase 2: per-node edge contraction P = relu1 @ Qn_tile[node] via MFMA.
__global__ __launch_bounds__(512) void fused_layer_k(
    const unsigned short* __restrict__ hb, const float* __restrict__ hpre,
    const float* __restrict__ bnsums, const float* __restrict__ gamma,
    const float* __restrict__ beta, int bn_mode,
    const unsigned short* __restrict__ Bp,
    const float* __restrict__ ea_s, const int* __restrict__ dst_s,
    const int* __restrict__ base, const float* __restrict__ W1,
    const float* __restrict__ b1, float* __restrict__ agg) {
  __shared__ unsigned short sA[16 * 136];
  __shared__ unsigned short sQ[16 * QS];
  __shared__ float sW1[EDF * HH];
  __shared__ float sb1[HH];
  __shared__ float sB2[16][17];
  __shared__ float sscl[HH], sshf[HH];

  int tid = threadIdx.x;
  int n0 = blockIdx.x * 16;
  int wid = tid >> 6, lane = tid & 63;
  int l15 = lane & 15, l4 = lane >> 4;

  for (int i = tid; i < EDF * HH; i += 512) sW1[i] = W1[i];
  if (tid < HH) sb1[tid] = b1[tid];
  if (bn_mode && tid < HH) {
    float mu = bnsums[tid] * (1.0f / NN);
    float var = bnsums[HH + tid] * (1.0f / NN) - mu * mu;
    float sc = gamma[tid] * rsqrtf(var + BN_EPS);
    sscl[tid] = sc;
    sshf[tid] = beta[tid] - mu * sc;
  }
  __syncthreads();

  // stage A tile (threads 0..255): thread -> node tid>>4, 8 halfs at col (tid&15)*8
  if (tid < 256) {
    int node = tid >> 4, c0 = (tid & 15) * 8;
    if (bn_mode == 0) {
      uint4 v = *(const uint4*)&hb[(size_t)(n0 + node) * HH + c0];
      *(uint4*)&sA[node * 136 + c0] = v;
    } else {
      float4 v0 = *(const float4*)&hpre[(size_t)(n0 + node) * HH + c0];
      float4 v1 = *(const float4*)&hpre[(size_t)(n0 + node) * HH + c0 + 4];
      short8 o;
#pragma unroll
      for (int j = 0; j < 4; ++j) {
        o[j] = (short)f2bf(fmaxf(0.f, fmaf((&v0.x)[j], sscl[c0 + j], sshf[c0 + j])));
        o[4 + j] = (short)f2bf(fmaxf(0.f, fmaf((&v1.x)[j], sscl[c0 + 4 + j], sshf[c0 + 4 + j])));
      }
      *(short8*)&sA[node * 136 + c0] = o;
    }
  }
  __syncthreads();

  // A-frags: a[ks] = A[node=l15][k=ks*32+l4*8 ..+8], reused across all ctiles
  short8 a0 = *(const short8*)&sA[l15 * 136 + 0 * 32 + l4 * 8];
  short8 a1 = *(const short8*)&sA[l15 * 136 + 1 * 32 + l4 * 8];
  short8 a2 = *(const short8*)&sA[l15 * 136 + 2 * 32 + l4 * 8];
  short8 a3 = *(const short8*)&sA[l15 * 136 + 3 * 32 + l4 * 8];

  // GEMM phase: wave w handles ctiles [w*16, w*16+16); ctile == k index
  int ctb = wid * 16;
#pragma unroll 4
  for (int ct = ctb; ct < ctb + 16; ++ct) {
    const unsigned short* bp = Bp + ((size_t)(ct * 16 + l15)) * HH + l4 * 8;
    short8 b0 = *(const short8*)(bp);
    short8 bv1 = *(const short8*)(bp + 32);
    short8 bv2 = *(const short8*)(bp + 64);
    short8 bv3 = *(const short8*)(bp + 96);
    f32x4 acc = {0.f, 0.f, 0.f, 0.f};
    acc = __builtin_amdgcn_mfma_f32_16x16x32_bf16(a0, b0, acc, 0, 0, 0);
    acc = __builtin_amdgcn_mfma_f32_16x16x32_bf16(a1, bv1, acc, 0, 0, 0);
    acc = __builtin_amdgcn_mfma_f32_16x16x32_bf16(a2, bv2, acc, 0, 0, 0);
    acc = __builtin_amdgcn_mfma_f32_16x16x32_bf16(a3, bv3, acc, 0, 0, 0);
    int kq = qperm(ct);
#pragma unroll
    for (int j = 0; j < 4; ++j)
      sQ[(l4 * 4 + j) * QS + kq * 16 + l15] = f2bf(acc[j]);
  }
  if (wid == 7) {  // B2 ctile: Bp rows 2048..2063
    const unsigned short* bp = Bp + ((size_t)(2048 + l15)) * HH + l4 * 8;
    short8 b0 = *(const short8*)(bp);
    short8 bv1 = *(const short8*)(bp + 32);
    short8 bv2 = *(const short8*)(bp + 64);
    short8 bv3 = *(const short8*)(bp + 96);
    f32x4 acc = {0.f, 0.f, 0.f, 0.f};
    acc = __builtin_amdgcn_mfma_f32_16x16x32_bf16(a0, b0, acc, 0, 0, 0);
    acc = __builtin_amdgcn_mfma_f32_16x16x32_bf16(a1, bv1, acc, 0, 0, 0);
    acc = __builtin_amdgcn_mfma_f32_16x16x32_bf16(a2, bv2, acc, 0, 0, 0);
    acc = __builtin_amdgcn_mfma_f32_16x16x32_bf16(a3, bv3, acc, 0, 0, 0);
#pragma unroll
    for (int j = 0; j < 4; ++j) sB2[l4 * 4 + j][l15] = acc[j];
  }
  __syncthreads();

  // Contract phase: wave handles 2 nodes sequentially
  for (int ni = 0; ni < 2; ++ni) {
    int nl = wid * 2 + ni;
    int n = n0 + nl;
    int i0 = base[n], i1 = base[n + 1];
    if (i0 == i1) continue;

    short8 qb[4];
#pragma unroll
    for (int ks = 0; ks < 4; ++ks)
#pragma unroll
      for (int j = 0; j < 8; ++j)
        qb[ks][j] = (short)sQ[nl * QS + qperm(ks * 32 + l4 * 8 + j) * 16 + l15];
    float b2v = sB2[nl][l15];

    for (int t0 = i0; t0 < i1; t0 += 16) {
      int row = t0 + l15;
      bool valid = row < i1;
      float4 eav = valid ? *(const float4*)&ea_s[(size_t)row * 4]
                         : make_float4(0.f, 0.f, 0.f, 0.f);
      f32x4 acc = {0.f, 0.f, 0.f, 0.f};
#pragma unroll
      for (int ks = 0; ks < 4; ++ks) {
        short8 a;
#pragma unroll
        for (int j = 0; j < 8; ++j) {
          int k = ks * 32 + l4 * 8 + j;
          float r = fmaf(eav.w, sW1[3 * HH + k],
                     fmaf(eav.z, sW1[2 * HH + k],
                       fmaf(eav.y, sW1[HH + k], fmaf(eav.x, sW1[k], sb1[k]))));
          a[j] = valid ? (short)f2bf(fmaxf(r, 0.f)) : (short)0;
        }
        acc = __builtin_amdgcn_mfma_f32_16x16x32_bf16(a, qb[ks], acc, 0, 0, 0);
      }
#pragma unroll
      for (int j = 0; j < 4; ++j) {
        int r = t0 + l4 * 4 + j;
        if (r < i1) {
          int dst = dst_s[r];
          atomicAdd(&agg[(size_t)dst * MM + l15], acc[j] + b2v);
        }
      }
    }
  }
}

// 16 nodes/block; optional inline BN+relu; zeroes its agg slice for next layer.
__global__ __launch_bounds__(256) void node_update_k(
    const float* __restrict__ hplain, const float* __restrict__ hsrc_pre,
    const float* __restrict__ bnsums, const float* __restrict__ gamma,
    const float* __restrict__ beta, int bn_mode,
    float* __restrict__ agg, const float* __restrict__ deg,
    const float* __restrict__ rootW, const float* __restrict__ cbias,
    const float* __restrict__ msgW, const float* __restrict__ msgb,
    float* __restrict__ hpre, float* __restrict__ sums) {
  __shared__ float srw[HH * MM];
  __shared__ float smw[MM * HH];
  __shared__ float sh[16][HH];
  __shared__ float xm[16][MM];
  __shared__ float scb[MM];
  __shared__ float smb[HH];
  __shared__ float red[256];
  __shared__ float sscl[HH], sshf[HH];
  int tid = threadIdx.x;
  int n0 = blockIdx.x * 16;
  for (int i = tid; i < HH * MM; i += 256) {
    srw[i] = rootW[i];
    smw[i] = msgW[i];
  }
  if (tid < MM) scb[tid] = cbias[tid];
  if (tid < HH) smb[tid] = msgb[tid];
  if (bn_mode && tid < HH) {
    float mu = bnsums[tid] * (1.0f / NN);
    float var = bnsums[HH + tid] * (1.0f / NN) - mu * mu;
    float sc = gamma[tid] * rsqrtf(var + BN_EPS);
    sscl[tid] = sc;
    sshf[tid] = beta[tid] - mu * sc;
  }
  __syncthreads();
  for (int i = tid; i < 16 * HH; i += 256) {
    int ni = i >> 7, c = i & 127;
    if (bn_mode) {
      float v = hsrc_pre[(size_t)(n0 + ni) * HH + c];
      sh[ni][c] = fmaxf(0.f, fmaf(v, sscl[c], sshf[c]));
    } else {
      sh[ni][c] = hplain[(size_t)(n0 + ni) * HH + c];
    }
  }
  __syncthreads();

  {
    int ni = tid >> 4, m = tid & 15;
    float s = 0.f;
#pragma unroll
    for (int k = 0; k < HH; ++k) s = fmaf(sh[ni][k], srw[k * MM + m], s);
    int n = n0 + ni;
    xm[ni][m] = agg[(size_t)n * MM + m] / fmaxf(deg[n], 1.0f) + s + scb[m];
  }
  __syncthreads();
  agg[(size_t)n0 * MM + tid] = 0.f;  // zero this block's slice for next layer

  int t = tid & 127;
  float lsum = 0.f, lss = 0.f;
#pragma unroll
  for (int pass = 0; pass < 8; ++pass) {
    int ni = pass * 2 + (tid >> 7);
    float hp = sh[ni][t] + smb[t];
#pragma unroll
    for (int m = 0; m < MM; ++m) hp = fmaf(xm[ni][m], smw[m * HH + t], hp);
    hpre[(size_t)(n0 + ni) * HH + t] = hp;
    lsum += hp;
    lss = fmaf(hp, hp, lss);
  }
  red[tid] = lsum;
  __syncthreads();
  if (tid < 128) atomicAdd(&sums[t], red[tid] + red[tid + 128]);
  __syncthreads();
  red[tid] = lss;
  __syncthreads();
  if (tid < 128) atomicAdd(&sums[HH + t], red[tid] + red[tid + 128]);
}

__global__ void out_proj_k(const float* __restrict__ hpre,
                           const float* __restrict__ bnsums,
                           const float* __restrict__ gamma,
                           const float* __restrict__ beta,
                           const float* __restrict__ W, const float* __restrict__ b,
                           float* __restrict__ out) {
  __shared__ float sscl[HH], sshf[HH];
  int tid = threadIdx.x;
  if (tid < HH) {
    float mu = bnsums[tid] * (1.0f / NN);
    float var = bnsums[HH + tid] * (1.0f / NN) - mu * mu;
    float sc = gamma[tid] * rsqrtf(var + BN_EPS);
    sscl[tid] = sc;
    sshf[tid] = beta[tid] - mu * sc;
  }
  __syncthreads();
  int n = blockIdx.x * 4 + (tid >> 6);
  int lane = tid & 63;
  if (n >= NN) return;
  float acc0 = 0.f, acc1 = 0.f, acc2 = 0.f, acc3 = 0.f;
#pragma unroll
  for (int rep = 0; rep < 2; ++rep) {
    int hh = lane + rep * 64;
    float hv = fmaxf(0.f, fmaf(hpre[(size_t)n * HH + hh], sscl[hh], sshf[hh]));
    acc0 = fmaf(hv, W[hh * OUTF + 0], acc0);
    acc1 = fmaf(hv, W[hh * OUTF + 1], acc1);
    acc2 = fmaf(hv, W[hh * OUTF + 2], acc2);
    acc3 = fmaf(hv, W[hh * OUTF + 3], acc3);
  }
#pragma unroll
  for (int s = 32; s > 0; s >>= 1) {
    acc0 += __shfl_down(acc0, s);
    acc1 += __shfl_down(acc1, s);
    acc2 += __shfl_down(acc2, s);
    acc3 += __shfl_down(acc3, s);
  }
  if (lane == 0) {
    out[n * OUTF + 0] = acc0 + b[0];
    out[n * OUTF + 1] = acc1 + b[1];
    out[n * OUTF + 2] = acc2 + b[2];
    out[n * OUTF + 3] = acc3 + b[3];
  }
}

extern "C" void kernel_launch(void* const* d_in, const int* in_sizes, int n_in,
                              void* d_out, int out_size, void* d_ws, size_t ws_size,
                              hipStream_t stream) {
  (void)in_sizes; (void)n_in; (void)out_size; (void)ws_size;
  const float* x    = (const float*)d_in[0];
  const int* ei     = (const int*)d_in[1];
  const float* ea   = (const float*)d_in[2];
  const float* inW  = (const float*)d_in[3];
  const float* inb  = (const float*)d_in[4];
  const float* cW1  = (const float*)d_in[5];
  const float* cb1  = (const float*)d_in[6];
  const float* cW2  = (const float*)d_in[7];
  const float* cb2  = (const float*)d_in[8];
  const float* rW   = (const float*)d_in[9];
  const float* cbias= (const float*)d_in[10];
  const float* gam  = (const float*)d_in[11];
  const float* bet  = (const float*)d_in[12];
  const float* mW   = (const float*)d_in[13];
  const float* mb   = (const float*)d_in[14];
  const float* oW   = (const float*)d_in[15];
  const float* ob   = (const float*)d_in[16];
  float* out = (float*)d_out;

  float* ws = (float*)d_ws;
  size_t off = 0;
  // contiguous zero region: deg, cnt, cur, agg, sums0, sums1
  float* deg   = ws + off; off += 8192;
  int* cnt     = (int*)(ws + off); off += 8192;
  int* cur     = (int*)(ws + off); off += 8192;
  float* agg   = ws + off; off += (size_t)NN * MM;
  float* sums0 = ws + off; off += 256;
  float* sums1 = ws + off; off += 256;
  size_t zero_floats = off;
  float* h     = ws + off; off += (size_t)NN * HH;
  float* hpre0 = ws + off; off += (size_t)NN * HH;
  float* hpre1 = ws + off; off += (size_t)NN * HH;
  unsigned short* hb = (unsigned short*)(ws + off); off += (size_t)NN * HH / 2;
  unsigned short* Bp = (unsigned short*)(ws + off); off += (size_t)NL * BPR * HH / 2;
  int* basev   = (int*)(ws + off); off += 8192;
  float* ea_s  = ws + off; off += (size_t)NE * 4;
  int* dst_s   = (int*)(ws + off); off += NE;

  hipMemsetAsync(deg, 0, zero_floats * sizeof(float), stream);
  front_k<<<NN, 128, 0, stream>>>(x, inW, inb, ei, cW2, cb2, h, hb, deg, cnt, Bp);
  scan_k<<<1, 1024, 0, stream>>>(cnt, basev);
  scatter_k<<<(NE + 255) / 256, 256, 0, stream>>>(ei, ea, basev, cur, ea_s, dst_s);

  // ---- layer 0 ----
  fused_layer_k<<<NN / 16, 512, 0, stream>>>(hb, hpre0, sums0, gam, bet, 0,
                                             Bp, ea_s, dst_s, basev, cW1, cb1, agg);
  node_update_k<<<NN / 16, 256, 0, stream>>>(h, hpre0, sums0, gam, bet, 0,
                                             agg, deg, rW, cbias, mW, mb,
                                             hpre0, sums0);
  // ---- layer 1 ----
  fused_layer_k<<<NN / 16, 512, 0, stream>>>(hb, hpre0, sums0, gam, bet, 1,
                                             Bp + (size_t)BPR * HH, ea_s, dst_s, basev,
                                             cW1 + EDF * HH, cb1 + HH, agg);
  node_update_k<<<NN / 16, 256, 0, stream>>>(h, hpre0, sums0, gam, bet, 1,
                                             agg, deg, rW + HH * MM, cbias + MM,
                                             mW + MM * HH, mb + HH,
                                             hpre1, sums1);
  out_proj_k<<<NN / 4, 256, 0, stream>>>(hpre1, sums1, gam + HH, bet + HH,
                                         oW, ob, out);
}

// Round 8
// 154.858 us; speedup vs baseline: 1.1506x; 1.0555x over previous
//
#include <hip/hip_runtime.h>

#define NN 8000
#define NPAD 8064
#define NE 64000
#define INF 16
#define HH 128
#define MM 16
#define EDF 4
#define OUTF 4
#define NL 2
#define BN_EPS 1e-5f
#define BPR 2064          // Bp rows per layer: 2048 qn-cols + 16 b2-cols

typedef __attribute__((ext_vector_type(8))) short short8;
typedef __attribute__((ext_vector_type(4))) float f32x4;

static __device__ __forceinline__ unsigned short f2bf(float f) {
  unsigned u = __builtin_bit_cast(unsigned, f);
  u = (u + 0x7fffu + ((u >> 16) & 1u)) >> 16;
  return (unsigned short)u;
}

// bijective k-permutation for contract LDS layout
static __device__ __forceinline__ int qperm(int k) {
  return ((k >> 3) & 3) | ((k & 7) << 2) | (k & 0x60);
}

// in_proj (all blocks) + edge counting (blocks 0..499) +
// coalesced Bp build (blocks 500..755 = W2 k-rows, 756..757 = b2 rows)
__global__ __launch_bounds__(128) void front_k(
    const float* __restrict__ x, const float* __restrict__ inW,
    const float* __restrict__ inb, const int* __restrict__ ei,
    const float* __restrict__ W2, const float* __restrict__ b2,
    float* __restrict__ h, unsigned short* __restrict__ hb,
    float* __restrict__ deg, int* __restrict__ cnt,
    unsigned short* __restrict__ Bp) {
  int blk = blockIdx.x;
  int t = threadIdx.x;
  __shared__ float sx[INF];
  if (t < INF) sx[t] = x[blk * INF + t];
  __syncthreads();
  float acc = inb[t];
#pragma unroll
  for (int i = 0; i < INF; ++i) acc = fmaf(sx[i], inW[i * HH + t], acc);
  h[(size_t)blk * HH + t] = acc;
  hb[(size_t)blk * HH + t] = f2bf(acc);

  if (blk < 500) {
    int e = blk * 128 + t;
    atomicAdd(&deg[ei[NE + e]], 1.0f);
    atomicAdd(&cnt[ei[e]], 1);
  } else if (blk < 756) {
    int r = blk - 500;            // 0..255
    int l = r >> 7, k = r & 127;
    const float* w2row = W2 + (size_t)l * (HH * HH * MM) + (size_t)k * 2048;
    float4 v0 = *(const float4*)&w2row[t * 16 + 0];
    float4 v1 = *(const float4*)&w2row[t * 16 + 4];
    float4 v2 = *(const float4*)&w2row[t * 16 + 8];
    float4 v3 = *(const float4*)&w2row[t * 16 + 12];
    unsigned short* bpr = Bp + ((size_t)l * BPR + (size_t)k * 16) * HH + t;
#pragma unroll
    for (int j = 0; j < 4; ++j) bpr[(0 + j) * HH] = f2bf((&v0.x)[j]);
#pragma unroll
    for (int j = 0; j < 4; ++j) bpr[(4 + j) * HH] = f2bf((&v1.x)[j]);
#pragma unroll
    for (int j = 0; j < 4; ++j) bpr[(8 + j) * HH] = f2bf((&v2.x)[j]);
#pragma unroll
    for (int j = 0; j < 4; ++j) bpr[(12 + j) * HH] = f2bf((&v3.x)[j]);
  } else if (blk < 758) {
    int l = blk - 756;
    const float* b2row = b2 + (size_t)l * 2048;
    float4 v0 = *(const float4*)&b2row[t * 16 + 0];
    float4 v1 = *(const float4*)&b2row[t * 16 + 4];
    float4 v2 = *(const float4*)&b2row[t * 16 + 8];
    float4 v3 = *(const float4*)&b2row[t * 16 + 12];
    unsigned short* bpr = Bp + ((size_t)l * BPR + 2048) * HH + t;
#pragma unroll
    for (int j = 0; j < 4; ++j) bpr[(0 + j) * HH] = f2bf((&v0.x)[j]);
#pragma unroll
    for (int j = 0; j < 4; ++j) bpr[(4 + j) * HH] = f2bf((&v1.x)[j]);
#pragma unroll
    for (int j = 0; j < 4; ++j) bpr[(8 + j) * HH] = f2bf((&v2.x)[j]);
#pragma unroll
    for (int j = 0; j < 4; ++j) bpr[(12 + j) * HH] = f2bf((&v3.x)[j]);
  }
}

__global__ __launch_bounds__(1024) void scan_k(const int* __restrict__ cnt,
                                               int* __restrict__ base) {
  __shared__ int part[1024];
  int t = threadIdx.x;
  int v[8], s = 0;
#pragma unroll
  for (int j = 0; j < 8; ++j) {
    int idx = t * 8 + j;
    v[j] = (idx < NN) ? cnt[idx] : 0;
    s += v[j];
  }
  part[t] = s;
  __syncthreads();
  for (int off = 1; off < 1024; off <<= 1) {
    int x = (t >= off) ? part[t - off] : 0;
    __syncthreads();
    part[t] += x;
    __syncthreads();
  }
  int ex = (t > 0) ? part[t - 1] : 0;
#pragma unroll
  for (int j = 0; j < 8; ++j) {
    int idx = t * 8 + j;
    if (idx < NN) base[idx] = ex;
    ex += v[j];
  }
  if (t == 1023) base[NN] = part[1023];
}

__global__ void scatter_k(const int* __restrict__ ei, const float* __restrict__ ea,
                          const int* __restrict__ base, int* __restrict__ cur,
                          float* __restrict__ ea_s, int* __restrict__ dst_s) {
  int e = blockIdx.x * blockDim.x + threadIdx.x;
  if (e < NE) {
    int src = ei[e];
    int p = base[src] + atomicAdd(&cur[src], 1);
    *(float4*)&ea_s[(size_t)p * 4] = *(const float4*)&ea[(size_t)e * 4];
    dst_s[p] = ei[NE + e];
  }
}

// Qn[NPAD x 2048](bf16) = A[NPAD x 128] @ Bp^T ; grid (17, 63).
// bn<16: Qn cols [bn*128,+128). bn==16: B2[NPAD x 16](f32) from Bp rows 2048..2063.
// A = hb (bn_mode 0) or BN_relu(hpre) (bn_mode 1), staged swizzled in LDS.
__global__ __launch_bounds__(256) void gemm_qn_k(
    const unsigned short* __restrict__ hb, const float* __restrict__ hpre,
    const float* __restrict__ bnsums, const float* __restrict__ gamma,
    const float* __restrict__ beta, int bn_mode,
    const unsigned short* __restrict__ Bp,
    unsigned short* __restrict__ Qn, float* __restrict__ B2) {
  __shared__ unsigned short sA[16384];
  __shared__ unsigned short sB[16384];
  int tid = threadIdx.x;
  int bm = blockIdx.y, bn = blockIdx.x;
  int r0 = bm * 128;

  // ---- A staging ----
  if (bn_mode == 0) {
#pragma unroll
    for (int rr = 0; rr < 8; ++rr) {
      int s = rr * 256 + tid;
      int row = s >> 4, k8 = s & 15;
      int n = r0 + row;
      uint4 v = make_uint4(0, 0, 0, 0);
      if (n < NN) v = *(const uint4*)&hb[(size_t)n * HH + k8 * 8];
      *(uint4*)&sA[(s ^ ((s >> 4) & 7)) * 8] = v;
    }
  } else {
    int k8 = tid & 15;
    int c0 = k8 * 8;
    float scl[8], shf[8];
#pragma unroll
    for (int j = 0; j < 8; ++j) {
      int c = c0 + j;
      float mu = bnsums[c] * (1.0f / NN);
      float var = bnsums[HH + c] * (1.0f / NN) - mu * mu;
      float sc = gamma[c] * rsqrtf(var + BN_EPS);
      scl[j] = sc;
      shf[j] = beta[c] - mu * sc;
    }
#pragma unroll
    for (int rr = 0; rr < 8; ++rr) {
      int s = rr * 256 + tid;
      int row = s >> 4;
      int n = r0 + row;
      short8 o = {0, 0, 0, 0, 0, 0, 0, 0};
      if (n < NN) {
        float4 v0 = *(const float4*)&hpre[(size_t)n * HH + c0];
        float4 v1 = *(const float4*)&hpre[(size_t)n * HH + c0 + 4];
#pragma unroll
        for (int j = 0; j < 4; ++j) {
          o[j] = (short)f2bf(fmaxf(0.f, fmaf((&v0.x)[j], scl[j], shf[j])));
          o[4 + j] = (short)f2bf(fmaxf(0.f, fmaf((&v1.x)[j], scl[4 + j], shf[4 + j])));
        }
      }
      *(short8*)&sA[(s ^ ((s >> 4) & 7)) * 8] = o;
    }
  }

  // ---- B staging: 128 contiguous bf16 rows from Bp (or 16 b2-rows + zeros) ----
  if (bn < 16) {
    const uint4* gB = (const uint4*)(Bp + (size_t)bn * 128 * HH);
#pragma unroll
    for (int rr = 0; rr < 8; ++rr) {
      int s = rr * 256 + tid;
      uint4 v = gB[s];
      *(uint4*)&sB[(s ^ ((s >> 4) & 7)) * 8] = v;
    }
  } else {
    const uint4* gB = (const uint4*)(Bp + (size_t)2048 * HH);
#pragma unroll
    for (int rr = 0; rr < 8; ++rr) {
      int s = rr * 256 + tid;
      int row = s >> 4;
      uint4 v = make_uint4(0, 0, 0, 0);
      if (row < 16) v = gB[s & 255];
      *(uint4*)&sB[(s ^ ((s >> 4) & 7)) * 8] = v;
    }
  }
  __syncthreads();

  int wid = tid >> 6, lane = tid & 63;
  int wr = (wid >> 1) * 64;
  int wc = (wid & 1) * 64;
  int l15 = lane & 15, l4 = lane >> 4;

  f32x4 acc[4][4] = {};
#pragma unroll
  for (int ks = 0; ks < 4; ++ks) {
    short8 af[4], bfr[4];
    int kb = ks * 4 + l4;
#pragma unroll
    for (int mr = 0; mr < 4; ++mr) {
      int r = wr + mr * 16 + l15;
      af[mr] = *(const short8*)&sA[(r * 16 + (kb ^ (r & 7))) * 8];
    }
#pragma unroll
    for (int nc = 0; nc < 4; ++nc) {
      int r = wc + nc * 16 + l15;
      bfr[nc] = *(const short8*)&sB[(r * 16 + (kb ^ (r & 7))) * 8];
    }
#pragma unroll
    for (int mr = 0; mr < 4; ++mr)
#pragma unroll
      for (int nc = 0; nc < 4; ++nc)
        acc[mr][nc] = __builtin_amdgcn_mfma_f32_16x16x32_bf16(af[mr], bfr[nc], acc[mr][nc], 0, 0, 0);
  }

  if (bn < 16) {
#pragma unroll
    for (int mr = 0; mr < 4; ++mr) {
      int rr0 = r0 + wr + mr * 16 + l4 * 4;
#pragma unroll
      for (int nc = 0; nc < 4; ++nc) {
        int c0 = bn * 128 + wc + nc * 16 + l15;
#pragma unroll
        for (int j = 0; j < 4; ++j)
          Qn[(size_t)(rr0 + j) * (HH * MM) + c0] = f2bf(acc[mr][nc][j]);
      }
    }
  } else if (wc == 0) {
#pragma unroll
    for (int mr = 0; mr < 4; ++mr) {
      int rr0 = r0 + wr + mr * 16 + l4 * 4;
#pragma unroll
      for (int j = 0; j < 4; ++j)
        B2[(size_t)(rr0 + j) * MM + l15] = acc[mr][0][j];
    }
  }
}

// One wave per src node (4 waves/block, 8 blocks/CU):
// P[d x 16] = relu1[d x 128] @ Qn[n][128 x 16] via MFMA; atomics into agg.
__global__ __launch_bounds__(256) void contract_k(const float* __restrict__ ea_s,
                                                  const int* __restrict__ dst_s,
                                                  const int* __restrict__ base,
                                                  const float* __restrict__ W1,
                                                  const float* __restrict__ b1,
                                                  const unsigned short* __restrict__ Qn,
                                                  const float* __restrict__ B2,
                                                  float* __restrict__ agg) {
  __shared__ float sW1[EDF * HH];
  __shared__ float sb1[HH];
  __shared__ unsigned short sQ[4][HH * MM];
  int tid = threadIdx.x;
  for (int i = tid; i < EDF * HH; i += 256) sW1[i] = W1[i];
  if (tid < HH) sb1[tid] = b1[tid];
  __syncthreads();

  int wid = tid >> 6, lane = tid & 63;
  int n = blockIdx.x * 4 + wid;
  int l15 = lane & 15, l4 = lane >> 4;
  int i0 = base[n], i1 = base[n + 1];
  if (i0 == i1) return;

  {
    const unsigned short* q = Qn + (size_t)n * (HH * MM);
#pragma unroll
    for (int rr = 0; rr < 2; ++rr) {
      int k = lane + rr * 64;
      uint4 lo = *(const uint4*)(q + k * 16);
      uint4 hi = *(const uint4*)(q + k * 16 + 8);
      int p = qperm(k) * 16;
      *(uint4*)&sQ[wid][p] = lo;
      *(uint4*)&sQ[wid][p + 8] = hi;
    }
  }
  float b2v = B2[(size_t)n * MM + l15];
  __builtin_amdgcn_s_waitcnt(0);  // wave-local LDS writes complete

  for (int t0 = i0; t0 < i1; t0 += 16) {
    int row = t0 + l15;
    bool valid = row < i1;
    float4 eav = valid ? *(const float4*)&ea_s[(size_t)row * 4]
                       : make_float4(0.f, 0.f, 0.f, 0.f);
    f32x4 acc = {0.f, 0.f, 0.f, 0.f};
#pragma unroll
    for (int ks = 0; ks < 4; ++ks) {
      short8 a, b;
#pragma unroll
      for (int j = 0; j < 8; ++j) {
        int k = ks * 32 + l4 * 8 + j;
        float r = fmaf(eav.w, sW1[3 * HH + k],
                   fmaf(eav.z, sW1[2 * HH + k],
                     fmaf(eav.y, sW1[HH + k], fmaf(eav.x, sW1[k], sb1[k]))));
        a[j] = valid ? (short)f2bf(fmaxf(r, 0.f)) : (short)0;
        b[j] = (short)sQ[wid][qperm(k) * 16 + l15];
      }
      acc = __builtin_amdgcn_mfma_f32_16x16x32_bf16(a, b, acc, 0, 0, 0);
    }
#pragma unroll
    for (int j = 0; j < 4; ++j) {
      int r = t0 + l4 * 4 + j;
      if (r < i1) {
        int dst = dst_s[r];
        atomicAdd(&agg[(size_t)dst * MM + l15], acc[j] + b2v);
      }
    }
  }
}

// 16 nodes/block; optional inline BN+relu; zeroes its agg slice for next layer.
__global__ __launch_bounds__(256) void node_update_k(
    const float* __restrict__ hplain, const float* __restrict__ hsrc_pre,
    const float* __restrict__ bnsums, const float* __restrict__ gamma,
    const float* __restrict__ beta, int bn_mode,
    float* __restrict__ agg, const float* __restrict__ deg,
    const float* __restrict__ rootW, const float* __restrict__ cbias,
    const float* __restrict__ msgW, const float* __restrict__ msgb,
    float* __restrict__ hpre, float* __restrict__ sums) {
  __shared__ float srw[HH * MM];
  __shared__ float smw[MM * HH];
  __shared__ float sh[16][HH];
  __shared__ float xm[16][MM];
  __shared__ float scb[MM];
  __shared__ float smb[HH];
  __shared__ float red[256];
  __shared__ float sscl[HH], sshf[HH];
  int tid = threadIdx.x;
  int n0 = blockIdx.x * 16;
  for (int i = tid; i < HH * MM; i += 256) {
    srw[i] = rootW[i];
    smw[i] = msgW[i];
  }
  if (tid < MM) scb[tid] = cbias[tid];
  if (tid < HH) smb[tid] = msgb[tid];
  if (bn_mode && tid < HH) {
    float mu = bnsums[tid] * (1.0f / NN);
    float var = bnsums[HH + tid] * (1.0f / NN) - mu * mu;
    float sc = gamma[tid] * rsqrtf(var + BN_EPS);
    sscl[tid] = sc;
    sshf[tid] = beta[tid] - mu * sc;
  }
  __syncthreads();
  for (int i = tid; i < 16 * HH; i += 256) {
    int ni = i >> 7, c = i & 127;
    if (bn_mode) {
      float v = hsrc_pre[(size_t)(n0 + ni) * HH + c];
      sh[ni][c] = fmaxf(0.f, fmaf(v, sscl[c], sshf[c]));
    } else {
      sh[ni][c] = hplain[(size_t)(n0 + ni) * HH + c];
    }
  }
  __syncthreads();

  {
    int ni = tid >> 4, m = tid & 15;
    float s = 0.f;
#pragma unroll
    for (int k = 0; k < HH; ++k) s = fmaf(sh[ni][k], srw[k * MM + m], s);
    int n = n0 + ni;
    xm[ni][m] = agg[(size_t)n * MM + m] / fmaxf(deg[n], 1.0f) + s + scb[m];
  }
  __syncthreads();
  agg[(size_t)n0 * MM + tid] = 0.f;  // zero this block's slice for next layer

  int t = tid & 127;
  float lsum = 0.f, lss = 0.f;
#pragma unroll
  for (int pass = 0; pass < 8; ++pass) {
    int ni = pass * 2 + (tid >> 7);
    float hp = sh[ni][t] + smb[t];
#pragma unroll
    for (int m = 0; m < MM; ++m) hp = fmaf(xm[ni][m], smw[m * HH + t], hp);
    hpre[(size_t)(n0 + ni) * HH + t] = hp;
    lsum += hp;
    lss = fmaf(hp, hp, lss);
  }
  red[tid] = lsum;
  __syncthreads();
  if (tid < 128) atomicAdd(&sums[t], red[tid] + red[tid + 128]);
  __syncthreads();
  red[tid] = lss;
  __syncthreads();
  if (tid < 128) atomicAdd(&sums[HH + t], red[tid] + red[tid + 128]);
}

__global__ void out_proj_k(const float* __restrict__ hpre,
                           const float* __restrict__ bnsums,
                           const float* __restrict__ gamma,
                           const float* __restrict__ beta,
                           const float* __restrict__ W, const float* __restrict__ b,
                           float* __restrict__ out) {
  __shared__ float sscl[HH], sshf[HH];
  int tid = threadIdx.x;
  if (tid < HH) {
    float mu = bnsums[tid] * (1.0f / NN);
    float var = bnsums[HH + tid] * (1.0f / NN) - mu * mu;
    float sc = gamma[tid] * rsqrtf(var + BN_EPS);
    sscl[tid] = sc;
    sshf[tid] = beta[tid] - mu * sc;
  }
  __syncthreads();
  int n = blockIdx.x * 4 + (tid >> 6);
  int lane = tid & 63;
  if (n >= NN) return;
  float acc0 = 0.f, acc1 = 0.f, acc2 = 0.f, acc3 = 0.f;
#pragma unroll
  for (int rep = 0; rep < 2; ++rep) {
    int hh = lane + rep * 64;
    float hv = fmaxf(0.f, fmaf(hpre[(size_t)n * HH + hh], sscl[hh], sshf[hh]));
    acc0 = fmaf(hv, W[hh * OUTF + 0], acc0);
    acc1 = fmaf(hv, W[hh * OUTF + 1], acc1);
    acc2 = fmaf(hv, W[hh * OUTF + 2], acc2);
    acc3 = fmaf(hv, W[hh * OUTF + 3], acc3);
  }
#pragma unroll
  for (int s = 32; s > 0; s >>= 1) {
    acc0 += __shfl_down(acc0, s);
    acc1 += __shfl_down(acc1, s);
    acc2 += __shfl_down(acc2, s);
    acc3 += __shfl_down(acc3, s);
  }
  if (lane == 0) {
    out[n * OUTF + 0] = acc0 + b[0];
    out[n * OUTF + 1] = acc1 + b[1];
    out[n * OUTF + 2] = acc2 + b[2];
    out[n * OUTF + 3] = acc3 + b[3];
  }
}

extern "C" void kernel_launch(void* const* d_in, const int* in_sizes, int n_in,
                              void* d_out, int out_size, void* d_ws, size_t ws_size,
                              hipStream_t stream) {
  (void)in_sizes; (void)n_in; (void)out_size; (void)ws_size;
  const float* x    = (const float*)d_in[0];
  const int* ei     = (const int*)d_in[1];
  const float* ea   = (const float*)d_in[2];
  const float* inW  = (const float*)d_in[3];
  const float* inb  = (const float*)d_in[4];
  const float* cW1  = (const float*)d_in[5];
  const float* cb1  = (const float*)d_in[6];
  const float* cW2  = (const float*)d_in[7];
  const float* cb2  = (const float*)d_in[8];
  const float* rW   = (const float*)d_in[9];
  const float* cbias= (const float*)d_in[10];
  const float* gam  = (const float*)d_in[11];
  const float* bet  = (const float*)d_in[12];
  const float* mW   = (const float*)d_in[13];
  const float* mb   = (const float*)d_in[14];
  const float* oW   = (const float*)d_in[15];
  const float* ob   = (const float*)d_in[16];
  float* out = (float*)d_out;

  float* ws = (float*)d_ws;
  size_t off = 0;
  // contiguous zero region: deg, cnt, cur, agg, sums0, sums1
  float* deg   = ws + off; off += 8192;
  int* cnt     = (int*)(ws + off); off += 8192;
  int* cur     = (int*)(ws + off); off += 8192;
  float* agg   = ws + off; off += (size_t)NN * MM;
  float* sums0 = ws + off; off += 256;
  float* sums1 = ws + off; off += 256;
  size_t zero_floats = off;
  float* h     = ws + off; off += (size_t)NN * HH;
  float* hpre0 = ws + off; off += (size_t)NN * HH;
  float* hpre1 = ws + off; off += (size_t)NN * HH;
  float* B2    = ws + off; off += (size_t)NPAD * MM;
  unsigned short* hb = (unsigned short*)(ws + off); off += (size_t)NN * HH / 2;
  unsigned short* Bp = (unsigned short*)(ws + off); off += (size_t)NL * BPR * HH / 2;
  unsigned short* Qn = (unsigned short*)(ws + off); off += (size_t)NPAD * HH * MM / 2;
  int* basev   = (int*)(ws + off); off += 8192;
  float* ea_s  = ws + off; off += (size_t)NE * 4;
  int* dst_s   = (int*)(ws + off); off += NE;

  hipMemsetAsync(deg, 0, zero_floats * sizeof(float), stream);
  front_k<<<NN, 128, 0, stream>>>(x, inW, inb, ei, cW2, cb2, h, hb, deg, cnt, Bp);
  scan_k<<<1, 1024, 0, stream>>>(cnt, basev);
  scatter_k<<<(NE + 255) / 256, 256, 0, stream>>>(ei, ea, basev, cur, ea_s, dst_s);

  dim3 gg(17, NPAD / 128);
  // ---- layer 0 ----
  gemm_qn_k<<<gg, 256, 0, stream>>>(hb, hpre0, sums0, gam, bet, 0, Bp, Qn, B2);
  contract_k<<<NN / 4, 256, 0, stream>>>(ea_s, dst_s, basev, cW1, cb1, Qn, B2, agg);
  node_update_k<<<NN / 16, 256, 0, stream>>>(h, hpre0, sums0, gam, bet, 0,
                                             agg, deg, rW, cbias, mW, mb,
                                             hpre0, sums0);
  // ---- layer 1 ----
  gemm_qn_k<<<gg, 256, 0, stream>>>(hb, hpre0, sums0, gam, bet, 1,
                                    Bp + (size_t)BPR * HH, Qn, B2);
  contract_k<<<NN / 4, 256, 0, stream>>>(ea_s, dst_s, basev, cW1 + EDF * HH,
                                         cb1 + HH, Qn, B2, agg);
  node_update_k<<<NN / 16, 256, 0, stream>>>(h, hpre0, sums0, gam, bet, 1,
                                             agg, deg, rW + HH * MM, cbias + MM,
                                             mW + MM * HH, mb + HH,
                                             hpre1, sums1);
  out_proj_k<<<NN / 4, 256, 0, stream>>>(hpre1, sums1, gam + HH, bet + HH,
                                         oW, ob, out);
}

// Round 9
// 147.875 us; speedup vs baseline: 1.2049x; 1.0472x over previous
//
#include <hip/hip_runtime.h>

#define NN 8000
#define NPAD 8064
#define NE 64000
#define INF 16
#define HH 128
#define MM 16
#define EDF 4
#define OUTF 4
#define NL 2
#define BN_EPS 1e-5f
#define BPR 2080          // Bp rows per layer: 2048 qn-cols + 16 b2-cols + 16 rootW-cols

typedef __attribute__((ext_vector_type(8))) short short8;
typedef __attribute__((ext_vector_type(4))) float f32x4;

static __device__ __forceinline__ unsigned short f2bf(float f) {
  unsigned u = __builtin_bit_cast(unsigned, f);
  u = (u + 0x7fffu + ((u >> 16) & 1u)) >> 16;
  return (unsigned short)u;
}
static __device__ __forceinline__ float bf2f(unsigned short s) {
  unsigned u = ((unsigned)s) << 16;
  return __builtin_bit_cast(float, u);
}

// bijective k-permutation for contract LDS layout, and its inverse
static __device__ __forceinline__ int qperm(int k) {
  return ((k >> 3) & 3) | ((k & 7) << 2) | (k & 0x60);
}
static __device__ __forceinline__ int qinv(int r) {
  return ((r & 3) << 3) | ((r >> 2) & 7) | (r & 0x60);
}

// in_proj (all blocks) + edge counting (0..499) + Bp build (500..759) + agg zero (760..884)
__global__ __launch_bounds__(128) void front_k(
    const float* __restrict__ x, const float* __restrict__ inW,
    const float* __restrict__ inb, const int* __restrict__ ei,
    const float* __restrict__ W2, const float* __restrict__ b2,
    const float* __restrict__ rW,
    unsigned short* __restrict__ hb,
    float* __restrict__ deg, int* __restrict__ cnt,
    unsigned short* __restrict__ Bp, float* __restrict__ agg) {
  int blk = blockIdx.x;
  int t = threadIdx.x;
  __shared__ float sx[INF];
  if (t < INF) sx[t] = x[blk * INF + t];
  __syncthreads();
  float acc = inb[t];
#pragma unroll
  for (int i = 0; i < INF; ++i) acc = fmaf(sx[i], inW[i * HH + t], acc);
  hb[(size_t)blk * HH + t] = f2bf(acc);

  if (blk < 500) {
    int e = blk * 128 + t;
    atomicAdd(&deg[ei[NE + e]], 1.0f);
    atomicAdd(&cnt[ei[e]], 1);
  } else if (blk < 756) {
    // transpose one W2 row k: read 2048 f32 contiguous, write 16 Bp rows coalesced
    int r = blk - 500;            // 0..255
    int l = r >> 7, k = r & 127;
    const float* w2row = W2 + (size_t)l * (HH * HH * MM) + (size_t)k * 2048;
    float4 v0 = *(const float4*)&w2row[t * 16 + 0];
    float4 v1 = *(const float4*)&w2row[t * 16 + 4];
    float4 v2 = *(const float4*)&w2row[t * 16 + 8];
    float4 v3 = *(const float4*)&w2row[t * 16 + 12];
    unsigned short* bpr = Bp + ((size_t)l * BPR + (size_t)k * 16) * HH + t;
#pragma unroll
    for (int j = 0; j < 4; ++j) bpr[(0 + j) * HH] = f2bf((&v0.x)[j]);
#pragma unroll
    for (int j = 0; j < 4; ++j) bpr[(4 + j) * HH] = f2bf((&v1.x)[j]);
#pragma unroll
    for (int j = 0; j < 4; ++j) bpr[(8 + j) * HH] = f2bf((&v2.x)[j]);
#pragma unroll
    for (int j = 0; j < 4; ++j) bpr[(12 + j) * HH] = f2bf((&v3.x)[j]);
  } else if (blk < 760) {
    // b2 rows (756,757) at Bp row 2048; rootW rows (758,759) at Bp row 2064
    int isroot = (blk >= 758);
    int l = (blk - 756) & 1;
    const float* src = isroot ? (rW + (size_t)l * HH * MM) : (b2 + (size_t)l * 2048);
    float4 v0 = *(const float4*)&src[t * 16 + 0];
    float4 v1 = *(const float4*)&src[t * 16 + 4];
    float4 v2 = *(const float4*)&src[t * 16 + 8];
    float4 v3 = *(const float4*)&src[t * 16 + 12];
    unsigned short* bpr = Bp + ((size_t)l * BPR + 2048 + isroot * 16) * HH + t;
#pragma unroll
    for (int j = 0; j < 4; ++j) bpr[(0 + j) * HH] = f2bf((&v0.x)[j]);
#pragma unroll
    for (int j = 0; j < 4; ++j) bpr[(4 + j) * HH] = f2bf((&v1.x)[j]);
#pragma unroll
    for (int j = 0; j < 4; ++j) bpr[(8 + j) * HH] = f2bf((&v2.x)[j]);
#pragma unroll
    for (int j = 0; j < 4; ++j) bpr[(12 + j) * HH] = f2bf((&v3.x)[j]);
  } else if (blk < 885) {
    // zero agg: 125 blocks x 128 thr x 2 uint4 = 32000 uint4 = NN*MM f32
    int i = (blk - 760) * 256 + t;
    uint4 z = make_uint4(0, 0, 0, 0);
    ((uint4*)agg)[i] = z;
    ((uint4*)agg)[i + 128] = z;
  }
}

__global__ __launch_bounds__(1024) void scan_k(const int* __restrict__ cnt,
                                               int* __restrict__ base) {
  __shared__ int part[1024];
  int t = threadIdx.x;
  int v[8], s = 0;
#pragma unroll
  for (int j = 0; j < 8; ++j) {
    int idx = t * 8 + j;
    v[j] = (idx < NN) ? cnt[idx] : 0;
    s += v[j];
  }
  part[t] = s;
  __syncthreads();
  for (int off = 1; off < 1024; off <<= 1) {
    int x = (t >= off) ? part[t - off] : 0;
    __syncthreads();
    part[t] += x;
    __syncthreads();
  }
  int ex = (t > 0) ? part[t - 1] : 0;
#pragma unroll
  for (int j = 0; j < 8; ++j) {
    int idx = t * 8 + j;
    if (idx < NN) base[idx] = ex;
    ex += v[j];
  }
  if (t == 1023) base[NN] = part[1023];
}

__global__ void scatter_k(const int* __restrict__ ei, const float* __restrict__ ea,
                          const int* __restrict__ base, int* __restrict__ cur,
                          float* __restrict__ ea_s, int* __restrict__ dst_s) {
  int e = blockIdx.x * blockDim.x + threadIdx.x;
  if (e < NE) {
    int src = ei[e];
    int p = base[src] + atomicAdd(&cur[src], 1);
    *(float4*)&ea_s[(size_t)p * 4] = *(const float4*)&ea[(size_t)e * 4];
    dst_s[p] = ei[NE + e];
  }
}

// Qn[NPAD x 2048](bf16) = A[NPAD x 128] @ Bp^T ; grid (17, 63).
// bn<16: Qn cols. bn==16: B2[NPAD x 16] (Bp rows 2048..2063) and
// Xroot[NPAD x 16] (Bp rows 2064..2079), both f32.
__global__ __launch_bounds__(256) void gemm_qn_k(
    const unsigned short* __restrict__ hb, const float* __restrict__ hpre,
    const float* __restrict__ bnsums, const float* __restrict__ gamma,
    const float* __restrict__ beta, int bn_mode,
    const unsigned short* __restrict__ Bp,
    unsigned short* __restrict__ Qn, float* __restrict__ B2,
    float* __restrict__ Xroot) {
  __shared__ unsigned short sA[16384];
  __shared__ unsigned short sB[16384];
  int tid = threadIdx.x;
  int bm = blockIdx.y, bn = blockIdx.x;
  int r0 = bm * 128;

  // ---- A staging ----
  if (bn_mode == 0) {
#pragma unroll
    for (int rr = 0; rr < 8; ++rr) {
      int s = rr * 256 + tid;
      int row = s >> 4, k8 = s & 15;
      int n = r0 + row;
      uint4 v = make_uint4(0, 0, 0, 0);
      if (n < NN) v = *(const uint4*)&hb[(size_t)n * HH + k8 * 8];
      *(uint4*)&sA[(s ^ ((s >> 4) & 7)) * 8] = v;
    }
  } else {
    int k8 = tid & 15;
    int c0 = k8 * 8;
    float scl[8], shf[8];
#pragma unroll
    for (int j = 0; j < 8; ++j) {
      int c = c0 + j;
      float mu = bnsums[c] * (1.0f / NN);
      float var = bnsums[HH + c] * (1.0f / NN) - mu * mu;
      float sc = gamma[c] * rsqrtf(var + BN_EPS);
      scl[j] = sc;
      shf[j] = beta[c] - mu * sc;
    }
#pragma unroll
    for (int rr = 0; rr < 8; ++rr) {
      int s = rr * 256 + tid;
      int row = s >> 4;
      int n = r0 + row;
      short8 o = {0, 0, 0, 0, 0, 0, 0, 0};
      if (n < NN) {
        float4 v0 = *(const float4*)&hpre[(size_t)n * HH + c0];
        float4 v1 = *(const float4*)&hpre[(size_t)n * HH + c0 + 4];
#pragma unroll
        for (int j = 0; j < 4; ++j) {
          o[j] = (short)f2bf(fmaxf(0.f, fmaf((&v0.x)[j], scl[j], shf[j])));
          o[4 + j] = (short)f2bf(fmaxf(0.f, fmaf((&v1.x)[j], scl[4 + j], shf[4 + j])));
        }
      }
      *(short8*)&sA[(s ^ ((s >> 4) & 7)) * 8] = o;
    }
  }

  // ---- B staging ----
  if (bn < 16) {
    const uint4* gB = (const uint4*)(Bp + (size_t)bn * 128 * HH);
#pragma unroll
    for (int rr = 0; rr < 8; ++rr) {
      int s = rr * 256 + tid;
      uint4 v = gB[s];
      *(uint4*)&sB[(s ^ ((s >> 4) & 7)) * 8] = v;
    }
  } else {
    const uint4* gB = (const uint4*)(Bp + (size_t)2048 * HH);
#pragma unroll
    for (int rr = 0; rr < 8; ++rr) {
      int s = rr * 256 + tid;
      int row = s >> 4;
      uint4 v = make_uint4(0, 0, 0, 0);
      if (row < 32) v = gB[s];
      *(uint4*)&sB[(s ^ ((s >> 4) & 7)) * 8] = v;
    }
  }
  __syncthreads();

  int wid = tid >> 6, lane = tid & 63;
  int wr = (wid >> 1) * 64;
  int wc = (wid & 1) * 64;
  int l15 = lane & 15, l4 = lane >> 4;

  f32x4 acc[4][4] = {};
#pragma unroll
  for (int ks = 0; ks < 4; ++ks) {
    short8 af[4], bfr[4];
    int kb = ks * 4 + l4;
#pragma unroll
    for (int mr = 0; mr < 4; ++mr) {
      int r = wr + mr * 16 + l15;
      af[mr] = *(const short8*)&sA[(r * 16 + (kb ^ (r & 7))) * 8];
    }
#pragma unroll
    for (int nc = 0; nc < 4; ++nc) {
      int r = wc + nc * 16 + l15;
      bfr[nc] = *(const short8*)&sB[(r * 16 + (kb ^ (r & 7))) * 8];
    }
#pragma unroll
    for (int mr = 0; mr < 4; ++mr)
#pragma unroll
      for (int nc = 0; nc < 4; ++nc)
        acc[mr][nc] = __builtin_amdgcn_mfma_f32_16x16x32_bf16(af[mr], bfr[nc], acc[mr][nc], 0, 0, 0);
  }

  if (bn < 16) {
#pragma unroll
    for (int mr = 0; mr < 4; ++mr) {
      int rr0 = r0 + wr + mr * 16 + l4 * 4;
#pragma unroll
      for (int nc = 0; nc < 4; ++nc) {
        int c0 = bn * 128 + wc + nc * 16 + l15;
#pragma unroll
        for (int j = 0; j < 4; ++j)
          Qn[(size_t)(rr0 + j) * (HH * MM) + c0] = f2bf(acc[mr][nc][j]);
      }
    }
  } else if (wc == 0) {
#pragma unroll
    for (int mr = 0; mr < 4; ++mr) {
      int rr0 = r0 + wr + mr * 16 + l4 * 4;
#pragma unroll
      for (int j = 0; j < 4; ++j) {
        B2[(size_t)(rr0 + j) * MM + l15] = acc[mr][0][j];
        Xroot[(size_t)(rr0 + j) * MM + l15] = acc[mr][1][j];
      }
    }
  }
}

// One wave per src node: P[d x 16] = relu1[d x 128] @ Qn[n][128 x 16] via MFMA.
// LDS staging: linear ds_write (conflict-free) + pre-permuted global source.
__global__ __launch_bounds__(256) void contract_k(const float* __restrict__ ea_s,
                                                  const int* __restrict__ dst_s,
                                                  const int* __restrict__ base,
                                                  const float* __restrict__ W1,
                                                  const float* __restrict__ b1,
                                                  const unsigned short* __restrict__ Qn,
                                                  const float* __restrict__ B2,
                                                  float* __restrict__ agg) {
  __shared__ float sW1[EDF * HH];
  __shared__ float sb1[HH];
  __shared__ unsigned short sQ[4][HH * MM];
  int tid = threadIdx.x;
  for (int i = tid; i < EDF * HH; i += 256) sW1[i] = W1[i];
  if (tid < HH) sb1[tid] = b1[tid];
  __syncthreads();

  int wid = tid >> 6, lane = tid & 63;
  int n = blockIdx.x * 4 + wid;
  int l15 = lane & 15, l4 = lane >> 4;
  int i0 = base[n], i1 = base[n + 1];
  if (i0 == i1) return;

  // stage Qn[n]: LDS row r holds Qn k=qinv(r); writes linear, source permuted
  {
    const unsigned short* q = Qn + (size_t)n * (HH * MM);
#pragma unroll
    for (int i = 0; i < 4; ++i) {
      int r = i * 32 + (lane >> 1);
      int c = (lane & 1) * 8;
      uint4 v = *(const uint4*)(q + qinv(r) * 16 + c);
      *(uint4*)&sQ[wid][i * 512 + lane * 8] = v;
    }
  }
  float b2v = B2[(size_t)n * MM + l15];
  __builtin_amdgcn_s_waitcnt(0);  // wave-local LDS writes complete

  for (int t0 = i0; t0 < i1; t0 += 16) {
    int row = t0 + l15;
    bool valid = row < i1;
    float4 eav = valid ? *(const float4*)&ea_s[(size_t)row * 4]
                       : make_float4(0.f, 0.f, 0.f, 0.f);
    f32x4 acc = {0.f, 0.f, 0.f, 0.f};
#pragma unroll
    for (int ks = 0; ks < 4; ++ks) {
      short8 a, b;
#pragma unroll
      for (int j = 0; j < 8; ++j) {
        int k = ks * 32 + l4 * 8 + j;
        float r = fmaf(eav.w, sW1[3 * HH + k],
                   fmaf(eav.z, sW1[2 * HH + k],
                     fmaf(eav.y, sW1[HH + k], fmaf(eav.x, sW1[k], sb1[k]))));
        a[j] = valid ? (short)f2bf(fmaxf(r, 0.f)) : (short)0;
        b[j] = (short)sQ[wid][qperm(k) * 16 + l15];
      }
      acc = __builtin_amdgcn_mfma_f32_16x16x32_bf16(a, b, acc, 0, 0, 0);
    }
#pragma unroll
    for (int j = 0; j < 4; ++j) {
      int r = t0 + l4 * 4 + j;
      if (r < i1) {
        int dst = dst_s[r];
        atomicAdd(&agg[(size_t)dst * MM + l15], acc[j] + b2v);
      }
    }
  }
}

// 16 nodes/block, slim: xm = agg/deg + Xroot + cbias ; hp = resid + xm@msgW + msgb
// fused BN partial sums; zeroes its agg slice for next layer.
__global__ __launch_bounds__(256) void node_update_k(
    const unsigned short* __restrict__ hb, const float* __restrict__ hsrc_pre,
    const float* __restrict__ bnsums, const float* __restrict__ gamma,
    const float* __restrict__ beta, int bn_mode,
    float* __restrict__ agg, const float* __restrict__ deg,
    const float* __restrict__ Xroot, const float* __restrict__ cbias,
    const float* __restrict__ msgW, const float* __restrict__ msgb,
    float* __restrict__ hpre, float* __restrict__ sums) {
  __shared__ float smw[MM * HH];
  __shared__ float xm[16][MM];
  __shared__ float scb[MM];
  __shared__ float smb[HH];
  __shared__ float red[256];
  __shared__ float sscl[HH], sshf[HH];
  int tid = threadIdx.x;
  int n0 = blockIdx.x * 16;
  for (int i = tid; i < MM * HH; i += 256) smw[i] = msgW[i];
  if (tid < MM) scb[tid] = cbias[tid];
  if (tid < HH) smb[tid] = msgb[tid];
  if (bn_mode && tid < HH) {
    float mu = bnsums[tid] * (1.0f / NN);
    float var = bnsums[HH + tid] * (1.0f / NN) - mu * mu;
    float sc = gamma[tid] * rsqrtf(var + BN_EPS);
    sscl[tid] = sc;
    sshf[tid] = beta[tid] - mu * sc;
  }
  __syncthreads();

  {
    int ni = tid >> 4, m = tid & 15;
    int n = n0 + ni;
    size_t idx = (size_t)n * MM + m;
    xm[ni][m] = agg[idx] / fmaxf(deg[n], 1.0f) + Xroot[idx] + scb[m];
  }
  __syncthreads();
  agg[(size_t)n0 * MM + tid] = 0.f;  // zero this block's slice for next layer

  int t = tid & 127;
  float lsum = 0.f, lss = 0.f;
#pragma unroll
  for (int pass = 0; pass < 8; ++pass) {
    int ni = pass * 2 + (tid >> 7);
    size_t idx = (size_t)(n0 + ni) * HH + t;
    float resid;
    if (bn_mode) {
      resid = fmaxf(0.f, fmaf(hsrc_pre[idx], sscl[t], sshf[t]));
    } else {
      resid = bf2f(hb[idx]);
    }
    float hp = resid + smb[t];
#pragma unroll
    for (int m = 0; m < MM; ++m) hp = fmaf(xm[ni][m], smw[m * HH + t], hp);
    hpre[idx] = hp;
    lsum += hp;
    lss = fmaf(hp, hp, lss);
  }
  red[tid] = lsum;
  __syncthreads();
  if (tid < 128) atomicAdd(&sums[t], red[tid] + red[tid + 128]);
  __syncthreads();
  red[tid] = lss;
  __syncthreads();
  if (tid < 128) atomicAdd(&sums[HH + t], red[tid] + red[tid + 128]);
}

__global__ void out_proj_k(const float* __restrict__ hpre,
                           const float* __restrict__ bnsums,
                           const float* __restrict__ gamma,
                           const float* __restrict__ beta,
                           const float* __restrict__ W, const float* __restrict__ b,
                           float* __restrict__ out) {
  __shared__ float sscl[HH], sshf[HH];
  int tid = threadIdx.x;
  if (tid < HH) {
    float mu = bnsums[tid] * (1.0f / NN);
    float var = bnsums[HH + tid] * (1.0f / NN) - mu * mu;
    float sc = gamma[tid] * rsqrtf(var + BN_EPS);
    sscl[tid] = sc;
    sshf[tid] = beta[tid] - mu * sc;
  }
  __syncthreads();
  int n = blockIdx.x * 4 + (tid >> 6);
  int lane = tid & 63;
  if (n >= NN) return;
  float acc0 = 0.f, acc1 = 0.f, acc2 = 0.f, acc3 = 0.f;
#pragma unroll
  for (int rep = 0; rep < 2; ++rep) {
    int hh = lane + rep * 64;
    float hv = fmaxf(0.f, fmaf(hpre[(size_t)n * HH + hh], sscl[hh], sshf[hh]));
    acc0 = fmaf(hv, W[hh * OUTF + 0], acc0);
    acc1 = fmaf(hv, W[hh * OUTF + 1], acc1);
    acc2 = fmaf(hv, W[hh * OUTF + 2], acc2);
    acc3 = fmaf(hv, W[hh * OUTF + 3], acc3);
  }
#pragma unroll
  for (int s = 32; s > 0; s >>= 1) {
    acc0 += __shfl_down(acc0, s);
    acc1 += __shfl_down(acc1, s);
    acc2 += __shfl_down(acc2, s);
    acc3 += __shfl_down(acc3, s);
  }
  if (lane == 0) {
    out[n * OUTF + 0] = acc0 + b[0];
    out[n * OUTF + 1] = acc1 + b[1];
    out[n * OUTF + 2] = acc2 + b[2];
    out[n * OUTF + 3] = acc3 + b[3];
  }
}

extern "C" void kernel_launch(void* const* d_in, const int* in_sizes, int n_in,
                              void* d_out, int out_size, void* d_ws, size_t ws_size,
                              hipStream_t stream) {
  (void)in_sizes; (void)n_in; (void)out_size; (void)ws_size;
  const float* x    = (const float*)d_in[0];
  const int* ei     = (const int*)d_in[1];
  const float* ea   = (const float*)d_in[2];
  const float* inW  = (const float*)d_in[3];
  const float* inb  = (const float*)d_in[4];
  const float* cW1  = (const float*)d_in[5];
  const float* cb1  = (const float*)d_in[6];
  const float* cW2  = (const float*)d_in[7];
  const float* cb2  = (const float*)d_in[8];
  const float* rW   = (const float*)d_in[9];
  const float* cbias= (const float*)d_in[10];
  const float* gam  = (const float*)d_in[11];
  const float* bet  = (const float*)d_in[12];
  const float* mW   = (const float*)d_in[13];
  const float* mb   = (const float*)d_in[14];
  const float* oW   = (const float*)d_in[15];
  const float* ob   = (const float*)d_in[16];
  float* out = (float*)d_out;

  float* ws = (float*)d_ws;
  size_t off = 0;
  // contiguous zero region: deg, cnt, cur, sums0, sums1 (one small memset)
  float* deg   = ws + off; off += 8192;
  int* cnt     = (int*)(ws + off); off += 8192;
  int* cur     = (int*)(ws + off); off += 8192;
  float* sums0 = ws + off; off += 256;
  float* sums1 = ws + off; off += 256;
  size_t zero_floats = off;
  float* agg   = ws + off; off += (size_t)NN * MM;      // zeroed by front_k
  float* hpre0 = ws + off; off += (size_t)NN * HH;
  float* hpre1 = ws + off; off += (size_t)NN * HH;
  float* B2    = ws + off; off += (size_t)NPAD * MM;
  float* Xroot = ws + off; off += (size_t)NPAD * MM;
  unsigned short* hb = (unsigned short*)(ws + off); off += (size_t)NN * HH / 2;
  unsigned short* Bp = (unsigned short*)(ws + off); off += (size_t)NL * BPR * HH / 2;
  unsigned short* Qn = (unsigned short*)(ws + off); off += (size_t)NPAD * HH * MM / 2;
  int* basev   = (int*)(ws + off); off += 8192;
  float* ea_s  = ws + off; off += (size_t)NE * 4;
  int* dst_s   = (int*)(ws + off); off += NE;

  hipMemsetAsync(deg, 0, zero_floats * sizeof(float), stream);
  front_k<<<NN, 128, 0, stream>>>(x, inW, inb, ei, cW2, cb2, rW, hb, deg, cnt, Bp, agg);
  scan_k<<<1, 1024, 0, stream>>>(cnt, basev);
  scatter_k<<<(NE + 255) / 256, 256, 0, stream>>>(ei, ea, basev, cur, ea_s, dst_s);

  dim3 gg(17, NPAD / 128);
  // ---- layer 0 ----
  gemm_qn_k<<<gg, 256, 0, stream>>>(hb, hpre0, sums0, gam, bet, 0, Bp, Qn, B2, Xroot);
  contract_k<<<NN / 4, 256, 0, stream>>>(ea_s, dst_s, basev, cW1, cb1, Qn, B2, agg);
  node_update_k<<<NN / 16, 256, 0, stream>>>(hb, hpre0, sums0, gam, bet, 0,
                                             agg, deg, Xroot, cbias, mW, mb,
                                             hpre0, sums0);
  // ---- layer 1 ----
  gemm_qn_k<<<gg, 256, 0, stream>>>(hb, hpre0, sums0, gam, bet, 1,
                                    Bp + (size_t)BPR * HH, Qn, B2, Xroot);
  contract_k<<<NN / 4, 256, 0, stream>>>(ea_s, dst_s, basev, cW1 + EDF * HH,
                                         cb1 + HH, Qn, B2, agg);
  node_update_k<<<NN / 16, 256, 0, stream>>>(hb, hpre0, sums0, gam, bet, 1,
                                             agg, deg, Xroot, cbias + MM,
                                             mW + MM * HH, mb + HH,
                                             hpre1, sums1);
  out_proj_k<<<NN / 4, 256, 0, stream>>>(hpre1, sums1, gam + HH, bet + HH,
                                         oW, ob, out);
}